// Round 1
// baseline (64418.878 us; speedup 1.0000x reference)
//
#include <hip/hip_runtime.h>
#include <hip/hip_cooperative_groups.h>
#include <math.h>

namespace cg = cooperative_groups;

#define T_STEPS 400
#define BATCH   32
#define HID     1024
#define MROWS   (T_STEPS * BATCH)   // 12800
#define NCLS    3500
#define NCHUNK  64                   // k-chunks in scan phase 1
#define KCH     16                   // K per chunk (NCHUNK*KCH == HID)

// ---------------- GEMM: C[M][N] = A[M][K] @ W[N][K]^T + bias[N] ----------------
// Requires K % 8 == 0, M % 128 == 0. N guarded.
#define BM 128
#define BN 128
#define BKQ 8

__global__ __launch_bounds__(256) void gemm_nt(
    const float* __restrict__ A, const float* __restrict__ W,
    const float* __restrict__ bias, float* __restrict__ C,
    int M, int N, int K) {
  __shared__ float As[BKQ][BM];
  __shared__ float Ws[BKQ][BN];
  const int tid = threadIdx.x;
  const int tx = tid & 15, ty = tid >> 4;
  const int m0 = blockIdx.y * BM, n0 = blockIdx.x * BN;
  const int ar = tid >> 1, aq = (tid & 1) * 4;

  float acc[8][8];
  #pragma unroll
  for (int i = 0; i < 8; ++i)
    #pragma unroll
    for (int j = 0; j < 8; ++j) acc[i][j] = 0.f;

  for (int k0 = 0; k0 < K; k0 += BKQ) {
    float4 av = *(const float4*)(A + (size_t)(m0 + ar) * K + k0 + aq);
    float4 wv = make_float4(0.f, 0.f, 0.f, 0.f);
    if (n0 + ar < N)
      wv = *(const float4*)(W + (size_t)(n0 + ar) * K + k0 + aq);
    __syncthreads();
    As[aq + 0][ar] = av.x; As[aq + 1][ar] = av.y;
    As[aq + 2][ar] = av.z; As[aq + 3][ar] = av.w;
    Ws[aq + 0][ar] = wv.x; Ws[aq + 1][ar] = wv.y;
    Ws[aq + 2][ar] = wv.z; Ws[aq + 3][ar] = wv.w;
    __syncthreads();
    #pragma unroll
    for (int k = 0; k < BKQ; ++k) {
      float a8[8], w8[8];
      *(float4*)&a8[0] = *(const float4*)&As[k][ty * 8];
      *(float4*)&a8[4] = *(const float4*)&As[k][ty * 8 + 4];
      *(float4*)&w8[0] = *(const float4*)&Ws[k][tx * 8];
      *(float4*)&w8[4] = *(const float4*)&Ws[k][tx * 8 + 4];
      #pragma unroll
      for (int i = 0; i < 8; ++i)
        #pragma unroll
        for (int j = 0; j < 8; ++j)
          acc[i][j] += a8[i] * w8[j];
    }
  }
  #pragma unroll
  for (int i = 0; i < 8; ++i) {
    int row = m0 + ty * 8 + i;
    #pragma unroll
    for (int j = 0; j < 8; ++j) {
      int col = n0 + tx * 8 + j;
      if (col < N)
        C[(size_t)row * N + col] = acc[i][j] + bias[col];
    }
  }
}

// ---------------- transpose 1024x1024: out[k][j] = in[j][k] ----------------
__global__ void transpose1024(const float* __restrict__ in, float* __restrict__ out) {
  __shared__ float tile[32][33];
  const int bx = blockIdx.x * 32, by = blockIdx.y * 32;
  const int tx = threadIdx.x, ty = threadIdx.y;  // 32 x 8
  #pragma unroll
  for (int i = 0; i < 32; i += 8)
    tile[ty + i][tx] = in[(size_t)(by + ty + i) * HID + bx + tx];
  __syncthreads();
  #pragma unroll
  for (int i = 0; i < 32; i += 8)
    out[(size_t)(bx + ty + i) * HID + by + tx] = tile[tx][ty + i];
}

// ---------------- cooperative scan over T for one layer ----------------
// phase1 (all 64 blocks): partial[kc][b][j] = sum_{k in chunk} h[t-1][b][k] * uhT[k][j]
// phase2 (blocks 0..31, block=b): at = wx + sum(partials); pre-swap; LN(ddof=1); relu
__global__ __launch_bounds__(1024) void scan_layer(
    const float* __restrict__ wx, const float* __restrict__ uhT,
    float* __restrict__ h_all, float* __restrict__ pre_all,
    float* __restrict__ part,
    const float* __restrict__ gamma, const float* __restrict__ beta,
    int skip_sub) {
  cg::grid_group grid = cg::this_grid();
  const int blk = blockIdx.x;
  const int tid = threadIdx.x;
  __shared__ float4 hs4[BATCH][KCH / 4];
  __shared__ float w1[16], w2[16];
  __shared__ float stats[2];

  for (int t = 0; t < T_STEPS; ++t) {
    if (t > 0) {
      if (tid < BATCH * (KCH / 4)) {
        int b = tid >> 2, q = tid & 3;
        hs4[b][q] = *(const float4*)(h_all + ((size_t)(t - 1) * BATCH + b) * HID
                                     + blk * KCH + q * 4);
      }
      __syncthreads();
      float u[KCH];
      #pragma unroll
      for (int kk = 0; kk < KCH; ++kk)
        u[kk] = uhT[(size_t)(blk * KCH + kk) * HID + tid];
      float pacc[BATCH];
      #pragma unroll
      for (int b = 0; b < BATCH; ++b) pacc[b] = 0.f;
      #pragma unroll
      for (int q = 0; q < KCH / 4; ++q) {
        #pragma unroll
        for (int b = 0; b < BATCH; ++b) {
          float4 hv = hs4[b][q];
          pacc[b] += hv.x * u[q * 4 + 0] + hv.y * u[q * 4 + 1]
                   + hv.z * u[q * 4 + 2] + hv.w * u[q * 4 + 3];
        }
      }
      #pragma unroll
      for (int b = 0; b < BATCH; ++b)
        part[((size_t)blk * BATCH + b) * HID + tid] = pacc[b];
    }
    grid.sync();
    if (blk < BATCH) {
      const int b = blk;
      const size_t base = ((size_t)t * BATCH + b) * HID + tid;
      float at = wx[base];
      if (t > 0) {
        #pragma unroll 8
        for (int kc = 0; kc < NCHUNK; ++kc)
          at += part[((size_t)kc * BATCH + b) * HID + tid];
      }
      float pre_old = skip_sub ? 0.f : pre_all[base];
      float a = at - pre_old;
      pre_all[base] = at;
      float s1 = a, s2 = a * a;
      #pragma unroll
      for (int off = 32; off; off >>= 1) {
        s1 += __shfl_down(s1, off);
        s2 += __shfl_down(s2, off);
      }
      const int lane = tid & 63, wid = tid >> 6;
      if (lane == 0) { w1[wid] = s1; w2[wid] = s2; }
      __syncthreads();
      if (tid == 0) {
        float t1 = 0.f, t2 = 0.f;
        #pragma unroll
        for (int w = 0; w < 16; ++w) { t1 += w1[w]; t2 += w2[w]; }
        float mean = t1 / (float)HID;
        float var = (t2 - (float)HID * mean * mean) / (float)(HID - 1);
        stats[0] = mean;
        stats[1] = sqrtf(fmaxf(var, 0.f)) + 1e-6f;  // std + EPS (torch-style)
      }
      __syncthreads();
      float mean = stats[0], denom = stats[1];
      float hn = gamma[tid] * (a - mean) / denom + beta[tid];
      h_all[base] = fmaxf(hn, 0.f);
    }
    grid.sync();
  }
}

// ---------------- softmax + loss/err per row ----------------
__global__ __launch_bounds__(256) void softmax_loss(
    float* __restrict__ out, const int* __restrict__ lab, float* __restrict__ acc) {
  __shared__ float rowbuf[NCLS];
  __shared__ float rv[4]; __shared__ int ri[4]; __shared__ float rs[4];
  __shared__ float shv[2];
  __shared__ int shidx;
  const int m = blockIdx.x;
  float* row = out + (size_t)m * NCLS;
  const int tid = threadIdx.x;
  const int lane = tid & 63, wid = tid >> 6;

  float vmax = -1e30f; int vidx = 0x7fffffff;
  for (int c = tid; c < NCLS; c += 256) {
    float v = row[c];
    rowbuf[c] = v;
    if (v > vmax) { vmax = v; vidx = c; }
  }
  #pragma unroll
  for (int off = 32; off; off >>= 1) {
    float ov = __shfl_down(vmax, off);
    int oi = __shfl_down(vidx, off);
    if (ov > vmax || (ov == vmax && oi < vidx)) { vmax = ov; vidx = oi; }
  }
  if (lane == 0) { rv[wid] = vmax; ri[wid] = vidx; }
  __syncthreads();
  if (tid == 0) {
    float bm = rv[0]; int bi = ri[0];
    for (int w = 1; w < 4; ++w)
      if (rv[w] > bm || (rv[w] == bm && ri[w] < bi)) { bm = rv[w]; bi = ri[w]; }
    shv[0] = bm; shidx = bi;
  }
  __syncthreads();
  float gmax = shv[0];
  float s = 0.f;
  for (int c = tid; c < NCLS; c += 256) s += expf(rowbuf[c] - gmax);
  #pragma unroll
  for (int off = 32; off; off >>= 1) s += __shfl_down(s, off);
  if (lane == 0) rs[wid] = s;
  __syncthreads();
  if (tid == 0) shv[1] = rs[0] + rs[1] + rs[2] + rs[3];
  __syncthreads();
  float lse = logf(shv[1]);
  for (int c = tid; c < NCLS; c += 256) row[c] = rowbuf[c] - gmax - lse;
  if (tid == 0) {
    int lb = lab[m];
    float nll = -(rowbuf[lb] - gmax - lse);
    atomicAdd(acc + 0, nll);
    atomicAdd(acc + 1, (shidx != lb) ? 1.f : 0.f);
  }
}

__global__ void init_acc(float* acc) { acc[threadIdx.x] = 0.f; }

__global__ void finalize_out(const float* __restrict__ acc, float* __restrict__ out) {
  out[0] = acc[0] * (1.f / (float)MROWS);
  out[1] = acc[1] * (1.f / (float)MROWS);
}

extern "C" void kernel_launch(void* const* d_in, const int* in_sizes, int n_in,
                              void* d_out, int out_size, void* d_ws, size_t ws_size,
                              hipStream_t stream) {
  const float* x     = (const float*)d_in[0];
  const int*   lab   = (const int*)d_in[1];
  const float* wx0_w = (const float*)d_in[3];
  const float* wx0_b = (const float*)d_in[4];
  const float* wx_w  = (const float*)d_in[5];
  const float* wx_b  = (const float*)d_in[6];
  const float* uh_w  = (const float*)d_in[7];
  const float* ln_g  = (const float*)d_in[8];
  const float* ln_b  = (const float*)d_in[9];
  const float* fco_w = (const float*)d_in[10];
  const float* fco_b = (const float*)d_in[11];
  float* out = (float*)d_out;

  float* wsf = (float*)d_ws;
  size_t off = 0;
  auto carve = [&](size_t n) { float* p = wsf + off; off += (n + 63) & ~(size_t)63; return p; };
  float* uhT   = carve((size_t)HID * HID);            //  4 MB
  float* wxbuf = carve((size_t)MROWS * HID);          // 52 MB
  float* h_all = carve((size_t)MROWS * HID);          // 52 MB
  float* pre   = carve((size_t)MROWS * HID);          // 52 MB
  float* part  = carve((size_t)NCHUNK * BATCH * HID); //  8 MB
  float* acc   = carve(64);

  init_acc<<<1, 2, 0, stream>>>(acc);

  for (int layer = 0; layer < 4; ++layer) {
    if (layer == 0) {
      gemm_nt<<<dim3(HID / BN, MROWS / BM), 256, 0, stream>>>(
          x, wx0_w, wx0_b, wxbuf, MROWS, HID, 440);
    } else {
      gemm_nt<<<dim3(HID / BN, MROWS / BM), 256, 0, stream>>>(
          h_all, wx_w + (size_t)(layer - 1) * HID * HID,
          wx_b + (size_t)(layer - 1) * HID, wxbuf, MROWS, HID, HID);
    }
    transpose1024<<<dim3(32, 32), dim3(32, 8), 0, stream>>>(
        uh_w + (size_t)layer * HID * HID, uhT);

    const float* wxc = wxbuf;
    const float* uc  = uhT;
    float* hc  = h_all;
    float* pc  = pre;
    float* ptc = part;
    const float* gc = ln_g + (size_t)layer * HID;
    const float* bc = ln_b + (size_t)layer * HID;
    int skip = (layer == 0) ? 1 : 0;
    void* args[] = { (void*)&wxc, (void*)&uc, (void*)&hc, (void*)&pc, (void*)&ptc,
                     (void*)&gc, (void*)&bc, (void*)&skip };
    hipLaunchCooperativeKernel((void*)scan_layer, dim3(NCHUNK), dim3(1024),
                               args, 0, stream);
  }

  gemm_nt<<<dim3((NCLS + BN - 1) / BN, MROWS / BM), 256, 0, stream>>>(
      h_all, fco_w, fco_b, out + 2, MROWS, NCLS, HID);
  softmax_loss<<<MROWS, 256, 0, stream>>>(out + 2, lab, acc);
  finalize_out<<<1, 1, 0, stream>>>(acc, out);
}

// Round 3
// 29625.238 us; speedup vs baseline: 2.1745x; 2.1745x over previous
//
#include <hip/hip_runtime.h>
#include <math.h>

#define T_STEPS 400
#define BATCH   32
#define HID     1024
#define MROWS   (T_STEPS * BATCH)   // 12800
#define NCLS    3500
#define NG      8                    // batch groups
#define BPG     4                    // batch rows per group
#define CPG     32                   // blocks (column slices) per group
#define JS      32                   // columns per block
#define EPS     1e-6f

// ---------------- GEMM: C[M][N] = A[M][K] @ W[N][K]^T + bias[N] ----------------
#define BM 128
#define BN 128
#define BKQ 8

__global__ __launch_bounds__(256) void gemm_nt(
    const float* __restrict__ A, const float* __restrict__ W,
    const float* __restrict__ bias, float* __restrict__ C,
    int M, int N, int K) {
  __shared__ float As[BKQ][BM];
  __shared__ float Ws[BKQ][BN];
  const int tid = threadIdx.x;
  const int tx = tid & 15, ty = tid >> 4;
  const int m0 = blockIdx.y * BM, n0 = blockIdx.x * BN;
  const int ar = tid >> 1, aq = (tid & 1) * 4;

  float acc[8][8];
  #pragma unroll
  for (int i = 0; i < 8; ++i)
    #pragma unroll
    for (int j = 0; j < 8; ++j) acc[i][j] = 0.f;

  for (int k0 = 0; k0 < K; k0 += BKQ) {
    float4 av = *(const float4*)(A + (size_t)(m0 + ar) * K + k0 + aq);
    float4 wv = make_float4(0.f, 0.f, 0.f, 0.f);
    if (n0 + ar < N)
      wv = *(const float4*)(W + (size_t)(n0 + ar) * K + k0 + aq);
    __syncthreads();
    As[aq + 0][ar] = av.x; As[aq + 1][ar] = av.y;
    As[aq + 2][ar] = av.z; As[aq + 3][ar] = av.w;
    Ws[aq + 0][ar] = wv.x; Ws[aq + 1][ar] = wv.y;
    Ws[aq + 2][ar] = wv.z; Ws[aq + 3][ar] = wv.w;
    __syncthreads();
    #pragma unroll
    for (int k = 0; k < BKQ; ++k) {
      float a8[8], w8[8];
      *(float4*)&a8[0] = *(const float4*)&As[k][ty * 8];
      *(float4*)&a8[4] = *(const float4*)&As[k][ty * 8 + 4];
      *(float4*)&w8[0] = *(const float4*)&Ws[k][tx * 8];
      *(float4*)&w8[4] = *(const float4*)&Ws[k][tx * 8 + 4];
      #pragma unroll
      for (int i = 0; i < 8; ++i)
        #pragma unroll
        for (int j = 0; j < 8; ++j)
          acc[i][j] += a8[i] * w8[j];
    }
  }
  #pragma unroll
  for (int i = 0; i < 8; ++i) {
    int row = m0 + ty * 8 + i;
    #pragma unroll
    for (int j = 0; j < 8; ++j) {
      int col = n0 + tx * 8 + j;
      if (col < N)
        C[(size_t)row * N + col] = acc[i][j] + bias[col];
    }
  }
}

// ---------------- transpose 1024x1024: out[k][j] = in[j][k] ----------------
__global__ void transpose1024(const float* __restrict__ in, float* __restrict__ out) {
  __shared__ float tile[32][33];
  const int bx = blockIdx.x * 32, by = blockIdx.y * 32;
  const int tx = threadIdx.x, ty = threadIdx.y;  // 32 x 8
  #pragma unroll
  for (int i = 0; i < 32; i += 8)
    tile[ty + i][tx] = in[(size_t)(by + ty + i) * HID + bx + tx];
  __syncthreads();
  #pragma unroll
  for (int i = 0; i < 32; i += 8)
    out[(size_t)(bx + ty + i) * HID + by + tx] = tile[tx][ty + i];
}

// ---------------- scan: 8 independent groups, flag-sync, Uh in registers ----------------
// grid = 256 blocks x 256 thr. group g = blk>>5 owns batch rows [4g,4g+4);
// block c = blk&31 owns columns [32c, 32c+32).
// thread map: jw = tid&3 (8-col octet), ks = tid>>2 (16-k strip). u regs = 16k x 8j.
__global__ __launch_bounds__(256, 1) void scan_layer(
    const float* __restrict__ wx, const float* __restrict__ uhT,
    float* __restrict__ h_all, float* __restrict__ pre_all,
    float* __restrict__ a_pub,        // [2][NG][BPG][HID]
    int* __restrict__ flags,          // [T_STEPS][NG]
    const float* __restrict__ gamma, const float* __restrict__ beta,
    int skip_sub) {
  const int tid  = threadIdx.x;
  const int g    = blockIdx.x >> 5;
  const int c    = blockIdx.x & 31;
  const int lane = tid & 63;
  const int wv   = tid >> 6;          // wave 0..3
  const int jw   = tid & 3;
  const int ks   = tid >> 2;          // 0..63
  const int col0 = c * JS + jw * 8;

  __shared__ float h_lds[HID][BPG];       // [k][b], 16KB
  __shared__ float partial[4][BPG][JS];   // per-wave partials, 2KB
  __shared__ float stats_lds[BPG][2];
  __shared__ float g_lds[HID], be_lds[HID];

  for (int k = tid; k < HID; k += 256) { g_lds[k] = gamma[k]; be_lds[k] = beta[k]; }

  // persistent Uh slice in registers: u[k in strip][8 cols]
  float4 u0[16], u1[16];
  #pragma unroll
  for (int i = 0; i < 16; ++i) {
    const float* p = uhT + (size_t)(ks * 16 + i) * HID + col0;
    u0[i] = *(const float4*)p;
    u1[i] = *(const float4*)(p + 4);
  }
  __syncthreads();

  for (int t = 0; t < T_STEPS; ++t) {
    const int par = t & 1;
    float* apub_t = a_pub + ((size_t)par * NG + g) * (BPG * HID);

    // issue wx / pre loads early (independent of h)
    float at0 = 0.f, pre_old = 0.f;
    size_t gidx = 0;
    if (tid < 128) {
      const int b = tid >> 5, j = tid & 31;
      gidx = ((size_t)t * BATCH + g * BPG + b) * HID + c * JS + j;
      at0 = wx[gidx];
      pre_old = skip_sub ? 0.f : pre_all[gidx];
    }

    if (t > 0) {
      float pacc[4][8];
      #pragma unroll
      for (int b = 0; b < 4; ++b)
        #pragma unroll
        for (int q = 0; q < 8; ++q) pacc[b][q] = 0.f;
      #pragma unroll
      for (int i = 0; i < 16; ++i) {
        float4 h4 = *(const float4*)&h_lds[ks * 16 + i][0];
        #pragma unroll
        for (int b = 0; b < 4; ++b) {
          float hb = ((const float*)&h4)[b];
          pacc[b][0] += hb * u0[i].x; pacc[b][1] += hb * u0[i].y;
          pacc[b][2] += hb * u0[i].z; pacc[b][3] += hb * u0[i].w;
          pacc[b][4] += hb * u1[i].x; pacc[b][5] += hb * u1[i].y;
          pacc[b][6] += hb * u1[i].z; pacc[b][7] += hb * u1[i].w;
        }
      }
      // reduce 16 k-strips within wave (lane bits 2..5)
      #pragma unroll
      for (int b = 0; b < 4; ++b)
        #pragma unroll
        for (int q = 0; q < 8; ++q) {
          float v = pacc[b][q];
          v += __shfl_xor(v, 4);
          v += __shfl_xor(v, 8);
          v += __shfl_xor(v, 16);
          v += __shfl_xor(v, 32);
          pacc[b][q] = v;
        }
      if ((lane >> 2) == 0) {   // lanes 0..3, one per jw
        #pragma unroll
        for (int b = 0; b < 4; ++b) {
          *(float4*)&partial[wv][b][jw * 8]     = *(const float4*)&pacc[b][0];
          *(float4*)&partial[wv][b][jw * 8 + 4] = *(const float4*)&pacc[b][4];
        }
      }
    }
    __syncthreads();

    // finalize a-slice and publish
    if (tid < 128) {
      const int b = tid >> 5, j = tid & 31;
      float red = 0.f;
      if (t > 0)
        red = partial[0][b][j] + partial[1][b][j] + partial[2][b][j] + partial[3][b][j];
      float at = at0 + red;
      pre_all[gidx] = at;
      apub_t[(size_t)b * HID + c * JS + j] = at - pre_old;
    }
    __syncthreads();

    if (tid == 0) {
      __threadfence();   // release: publish a-slice before flag bump
      int* fl = flags + t * NG + g;
      __hip_atomic_fetch_add(fl, 1, __ATOMIC_RELAXED, __HIP_MEMORY_SCOPE_AGENT);
      while (__hip_atomic_load(fl, __ATOMIC_RELAXED, __HIP_MEMORY_SCOPE_AGENT) < CPG)
        __builtin_amdgcn_s_sleep(1);
      __threadfence();   // acquire: flag seen before reading others' slices
    }
    __syncthreads();

    // stats per batch row (wave wv <-> row b=wv), ddof=1, eps on std
    {
      const float* arow = apub_t + (size_t)wv * HID;
      float s1 = 0.f, s2 = 0.f;
      #pragma unroll
      for (int i = 0; i < 16; ++i) {
        float v = arow[i * 64 + lane];
        s1 += v; s2 += v * v;
      }
      #pragma unroll
      for (int m = 1; m <= 32; m <<= 1) { s1 += __shfl_xor(s1, m); s2 += __shfl_xor(s2, m); }
      if (lane == 0) {
        float mean = s1 * (1.f / HID);
        float var = (s2 - (float)HID * mean * mean) * (1.f / (float)(HID - 1));
        stats_lds[wv][0] = mean;
        stats_lds[wv][1] = sqrtf(fmaxf(var, 0.f)) + EPS;
      }
    }
    __syncthreads();

    // h = relu(LN(a)) for k-quad [tid*4, tid*4+4), all 4 rows; write [k][b] layout
    {
      const int k0 = tid * 4;
      float4 g4 = *(const float4*)&g_lds[k0];
      float4 b4 = *(const float4*)&be_lds[k0];
      float hq[4][4];
      #pragma unroll
      for (int b = 0; b < 4; ++b) {
        float mean = stats_lds[b][0];
        float rd = 1.f / stats_lds[b][1];
        float4 a4 = *(const float4*)&apub_t[(size_t)b * HID + k0];
        hq[b][0] = fmaxf(g4.x * (a4.x - mean) * rd + b4.x, 0.f);
        hq[b][1] = fmaxf(g4.y * (a4.y - mean) * rd + b4.y, 0.f);
        hq[b][2] = fmaxf(g4.z * (a4.z - mean) * rd + b4.z, 0.f);
        hq[b][3] = fmaxf(g4.w * (a4.w - mean) * rd + b4.w, 0.f);
      }
      #pragma unroll
      for (int r = 0; r < 4; ++r)
        *(float4*)&h_lds[k0 + r][0] = make_float4(hq[0][r], hq[1][r], hq[2][r], hq[3][r]);
      if (c == 0) {
        #pragma unroll
        for (int b = 0; b < 4; ++b)
          *(float4*)&h_all[((size_t)t * BATCH + g * BPG + b) * HID + k0] =
              make_float4(hq[b][0], hq[b][1], hq[b][2], hq[b][3]);
      }
    }
    __syncthreads();
  }
}

// ---------------- softmax + loss/err per row ----------------
__global__ __launch_bounds__(256) void softmax_loss(
    float* __restrict__ out, const int* __restrict__ lab, float* __restrict__ acc) {
  __shared__ float rowbuf[NCLS];
  __shared__ float rv[4]; __shared__ int ri[4]; __shared__ float rs[4];
  __shared__ float shv[2];
  __shared__ int shidx;
  const int m = blockIdx.x;
  float* row = out + (size_t)m * NCLS;
  const int tid = threadIdx.x;
  const int lane = tid & 63, wid = tid >> 6;

  float vmax = -1e30f; int vidx = 0x7fffffff;
  for (int c = tid; c < NCLS; c += 256) {
    float v = row[c];
    rowbuf[c] = v;
    if (v > vmax) { vmax = v; vidx = c; }
  }
  #pragma unroll
  for (int off = 32; off; off >>= 1) {
    float ov = __shfl_down(vmax, off);
    int oi = __shfl_down(vidx, off);
    if (ov > vmax || (ov == vmax && oi < vidx)) { vmax = ov; vidx = oi; }
  }
  if (lane == 0) { rv[wid] = vmax; ri[wid] = vidx; }
  __syncthreads();
  if (tid == 0) {
    float bm = rv[0]; int bi = ri[0];
    for (int w = 1; w < 4; ++w)
      if (rv[w] > bm || (rv[w] == bm && ri[w] < bi)) { bm = rv[w]; bi = ri[w]; }
    shv[0] = bm; shidx = bi;
  }
  __syncthreads();
  float gmax = shv[0];
  float s = 0.f;
  for (int c = tid; c < NCLS; c += 256) s += expf(rowbuf[c] - gmax);
  #pragma unroll
  for (int off = 32; off; off >>= 1) s += __shfl_down(s, off);
  if (lane == 0) rs[wid] = s;
  __syncthreads();
  if (tid == 0) shv[1] = rs[0] + rs[1] + rs[2] + rs[3];
  __syncthreads();
  float lse = logf(shv[1]);
  for (int c = tid; c < NCLS; c += 256) row[c] = rowbuf[c] - gmax - lse;
  if (tid == 0) {
    int lb = lab[m];
    float nll = -(rowbuf[lb] - gmax - lse);
    atomicAdd(acc + 0, nll);
    atomicAdd(acc + 1, (shidx != lb) ? 1.f : 0.f);
  }
}

__global__ void init_acc(float* acc) { acc[threadIdx.x] = 0.f; }

__global__ void finalize_out(const float* __restrict__ acc, float* __restrict__ out) {
  out[0] = acc[0] * (1.f / (float)MROWS);
  out[1] = acc[1] * (1.f / (float)MROWS);
}

extern "C" void kernel_launch(void* const* d_in, const int* in_sizes, int n_in,
                              void* d_out, int out_size, void* d_ws, size_t ws_size,
                              hipStream_t stream) {
  const float* x     = (const float*)d_in[0];
  const int*   lab   = (const int*)d_in[1];
  const float* wx0_w = (const float*)d_in[3];
  const float* wx0_b = (const float*)d_in[4];
  const float* wx_w  = (const float*)d_in[5];
  const float* wx_b  = (const float*)d_in[6];
  const float* uh_w  = (const float*)d_in[7];
  const float* ln_g  = (const float*)d_in[8];
  const float* ln_b  = (const float*)d_in[9];
  const float* fco_w = (const float*)d_in[10];
  const float* fco_b = (const float*)d_in[11];
  float* out = (float*)d_out;

  float* wsf = (float*)d_ws;
  size_t off = 0;
  auto carve = [&](size_t n) { float* p = wsf + off; off += (n + 63) & ~(size_t)63; return p; };
  float* uhT   = carve((size_t)HID * HID);                 //  4 MB
  float* wxbuf = carve((size_t)MROWS * HID);               // 50 MB
  float* h_all = carve((size_t)MROWS * HID);               // 50 MB
  float* pre   = carve((size_t)MROWS * HID);               // 50 MB
  float* a_pub = carve((size_t)2 * NG * BPG * HID);        // 256 KB
  int*   flags = (int*)carve((size_t)4 * T_STEPS * NG);    // 51 KB
  float* acc   = carve(64);

  (void)hipMemsetAsync(flags, 0, (size_t)4 * T_STEPS * NG * sizeof(int), stream);
  init_acc<<<1, 2, 0, stream>>>(acc);

  for (int layer = 0; layer < 4; ++layer) {
    if (layer == 0) {
      gemm_nt<<<dim3(HID / BN, MROWS / BM), 256, 0, stream>>>(
          x, wx0_w, wx0_b, wxbuf, MROWS, HID, 440);
    } else {
      gemm_nt<<<dim3(HID / BN, MROWS / BM), 256, 0, stream>>>(
          h_all, wx_w + (size_t)(layer - 1) * HID * HID,
          wx_b + (size_t)(layer - 1) * HID, wxbuf, MROWS, HID, HID);
    }
    transpose1024<<<dim3(32, 32), dim3(32, 8), 0, stream>>>(
        uh_w + (size_t)layer * HID * HID, uhT);

    scan_layer<<<dim3(NG * CPG), 256, 0, stream>>>(
        wxbuf, uhT, h_all, pre, a_pub, flags + layer * T_STEPS * NG,
        ln_g + (size_t)layer * HID, ln_b + (size_t)layer * HID,
        (layer == 0) ? 1 : 0);
  }

  gemm_nt<<<dim3((NCLS + BN - 1) / BN, MROWS / BM), 256, 0, stream>>>(
      h_all, fco_w, fco_b, out + 2, MROWS, NCLS, HID);
  softmax_loss<<<MROWS, 256, 0, stream>>>(out + 2, lab, acc);
  finalize_out<<<1, 1, 0, stream>>>(acc, out);
}

// Round 4
// 17512.833 us; speedup vs baseline: 3.6784x; 1.6916x over previous
//
#include <hip/hip_runtime.h>
#include <math.h>

#define T_STEPS 400
#define BATCH   32
#define HID     1024
#define MROWS   (T_STEPS * BATCH)   // 12800
#define NCLS    3500
#define NG      8                    // batch groups
#define BPG     4                    // batch rows per group
#define CPG     32                   // blocks (column slices) per group
#define JS      32                   // columns per block
#define EPS     1e-6f

// ---------------- GEMM: C[M][N] = A[M][K] @ W[N][K]^T + bias[N] ----------------
#define BM 128
#define BN 128
#define BKQ 8

__global__ __launch_bounds__(256) void gemm_nt(
    const float* __restrict__ A, const float* __restrict__ W,
    const float* __restrict__ bias, float* __restrict__ C,
    int M, int N, int K) {
  __shared__ float As[BKQ][BM];
  __shared__ float Ws[BKQ][BN];
  const int tid = threadIdx.x;
  const int tx = tid & 15, ty = tid >> 4;
  const int m0 = blockIdx.y * BM, n0 = blockIdx.x * BN;
  const int ar = tid >> 1, aq = (tid & 1) * 4;

  float acc[8][8];
  #pragma unroll
  for (int i = 0; i < 8; ++i)
    #pragma unroll
    for (int j = 0; j < 8; ++j) acc[i][j] = 0.f;

  for (int k0 = 0; k0 < K; k0 += BKQ) {
    float4 av = *(const float4*)(A + (size_t)(m0 + ar) * K + k0 + aq);
    float4 wv = make_float4(0.f, 0.f, 0.f, 0.f);
    if (n0 + ar < N)
      wv = *(const float4*)(W + (size_t)(n0 + ar) * K + k0 + aq);
    __syncthreads();
    As[aq + 0][ar] = av.x; As[aq + 1][ar] = av.y;
    As[aq + 2][ar] = av.z; As[aq + 3][ar] = av.w;
    Ws[aq + 0][ar] = wv.x; Ws[aq + 1][ar] = wv.y;
    Ws[aq + 2][ar] = wv.z; Ws[aq + 3][ar] = wv.w;
    __syncthreads();
    #pragma unroll
    for (int k = 0; k < BKQ; ++k) {
      float a8[8], w8[8];
      *(float4*)&a8[0] = *(const float4*)&As[k][ty * 8];
      *(float4*)&a8[4] = *(const float4*)&As[k][ty * 8 + 4];
      *(float4*)&w8[0] = *(const float4*)&Ws[k][tx * 8];
      *(float4*)&w8[4] = *(const float4*)&Ws[k][tx * 8 + 4];
      #pragma unroll
      for (int i = 0; i < 8; ++i)
        #pragma unroll
        for (int j = 0; j < 8; ++j)
          acc[i][j] += a8[i] * w8[j];
    }
  }
  #pragma unroll
  for (int i = 0; i < 8; ++i) {
    int row = m0 + ty * 8 + i;
    #pragma unroll
    for (int j = 0; j < 8; ++j) {
      int col = n0 + tx * 8 + j;
      if (col < N)
        C[(size_t)row * N + col] = acc[i][j] + bias[col];
    }
  }
}

// ---------------- transpose 1024x1024: out[k][j] = in[j][k] ----------------
__global__ void transpose1024(const float* __restrict__ in, float* __restrict__ out) {
  __shared__ float tile[32][33];
  const int bx = blockIdx.x * 32, by = blockIdx.y * 32;
  const int tx = threadIdx.x, ty = threadIdx.y;  // 32 x 8
  #pragma unroll
  for (int i = 0; i < 32; i += 8)
    tile[ty + i][tx] = in[(size_t)(by + ty + i) * HID + bx + tx];
  __syncthreads();
  #pragma unroll
  for (int i = 0; i < 32; i += 8)
    out[(size_t)(bx + ty + i) * HID + by + tx] = tile[tx][ty + i];
}

// ---------------- scan: flag-sync via IF-coherent atomics, no fences ----------------
// grid = 256 blocks x 256 thr. group g = blk>>5 owns batch rows [4g,4g+4);
// block c = blk&31 owns columns [32c, 32c+32).
// matvec thread map: jw = tid&3 (8-col octet), ks = tid>>2; thread's k-rows = ks + 64*i.
// LN thread map: k-rows = tid + 256*j.
__global__ __launch_bounds__(256, 1) void scan_layer(
    const float* __restrict__ wx, const float* __restrict__ uhT,
    float* __restrict__ h_all, float* __restrict__ pre_all,
    float* __restrict__ a_pub,        // [2][NG][BPG][HID]
    int* __restrict__ flags,          // [T_STEPS][NG]
    const float* __restrict__ gamma, const float* __restrict__ beta,
    int skip_sub) {
  const int tid  = threadIdx.x;
  const int g    = blockIdx.x >> 5;
  const int c    = blockIdx.x & 31;
  const int lane = tid & 63;
  const int wv   = tid >> 6;          // wave 0..3
  const int jw   = tid & 3;
  const int ks   = tid >> 2;          // 0..63
  const int col0 = c * JS + jw * 8;

  __shared__ float h_lds[HID * BPG];      // flat [k*4+b], 16KB
  __shared__ float a_lds[BPG * HID];      // flat [b*1024+k], 16KB
  __shared__ float partial[4][BPG][JS];   // per-wave partials, 2KB
  __shared__ float stats_lds[BPG][2];
  __shared__ float g_lds[HID], be_lds[HID];

  for (int k = tid; k < HID; k += 256) { g_lds[k] = gamma[k]; be_lds[k] = beta[k]; }

  // persistent Uh slice in registers: rows ks+64i, cols col0..col0+7
  float4 u0[16], u1[16];
  #pragma unroll
  for (int i = 0; i < 16; ++i) {
    const float* p = uhT + (size_t)(ks + 64 * i) * HID + col0;
    u0[i] = *(const float4*)p;
    u1[i] = *(const float4*)(p + 4);
  }
  __syncthreads();

  for (int t = 0; t < T_STEPS; ++t) {
    const int par = t & 1;
    float* apub_t = a_pub + ((size_t)par * NG + g) * (BPG * HID);

    // issue wx / pre loads early (independent of h)
    float at0 = 0.f, pre_old = 0.f;
    size_t gidx = 0;
    if (tid < 128) {
      const int b = tid >> 5, j = tid & 31;
      gidx = ((size_t)t * BATCH + g * BPG + b) * HID + c * JS + j;
      at0 = wx[gidx];
      pre_old = skip_sub ? 0.f : pre_all[gidx];
    }

    if (t > 0) {
      float pacc[4][8];
      #pragma unroll
      for (int b = 0; b < 4; ++b)
        #pragma unroll
        for (int q = 0; q < 8; ++q) pacc[b][q] = 0.f;
      #pragma unroll
      for (int i = 0; i < 16; ++i) {
        float4 h4 = *(const float4*)&h_lds[(ks + 64 * i) * 4];  // 2-way: free
        #pragma unroll
        for (int b = 0; b < 4; ++b) {
          float hb = ((const float*)&h4)[b];
          pacc[b][0] += hb * u0[i].x; pacc[b][1] += hb * u0[i].y;
          pacc[b][2] += hb * u0[i].z; pacc[b][3] += hb * u0[i].w;
          pacc[b][4] += hb * u1[i].x; pacc[b][5] += hb * u1[i].y;
          pacc[b][6] += hb * u1[i].z; pacc[b][7] += hb * u1[i].w;
        }
      }
      // reduce 16 k-strips within wave (lane bits 2..5)
      #pragma unroll
      for (int b = 0; b < 4; ++b)
        #pragma unroll
        for (int q = 0; q < 8; ++q) {
          float v = pacc[b][q];
          v += __shfl_xor(v, 4);
          v += __shfl_xor(v, 8);
          v += __shfl_xor(v, 16);
          v += __shfl_xor(v, 32);
          pacc[b][q] = v;
        }
      if ((lane >> 2) == 0) {   // lanes 0..3, one per jw
        #pragma unroll
        for (int b = 0; b < 4; ++b) {
          *(float4*)&partial[wv][b][jw * 8]     = *(const float4*)&pacc[b][0];
          *(float4*)&partial[wv][b][jw * 8 + 4] = *(const float4*)&pacc[b][4];
        }
      }
    }
    __syncthreads();

    // finalize a-slice; publish via IF-coherent relaxed atomic stores (no fence)
    if (tid < 128) {
      const int b = tid >> 5, j = tid & 31;
      float red = 0.f;
      if (t > 0)
        red = partial[0][b][j] + partial[1][b][j] + partial[2][b][j] + partial[3][b][j];
      float at = at0 + red;
      pre_all[gidx] = at;
      __hip_atomic_store(&apub_t[(size_t)b * HID + c * JS + j], at - pre_old,
                         __ATOMIC_RELAXED, __HIP_MEMORY_SCOPE_AGENT);
    }
    // each thread drains its own outstanding stores before the barrier
    asm volatile("s_waitcnt vmcnt(0)" ::: "memory");
    __syncthreads();

    if (tid == 0) {
      int* fl = flags + t * NG + g;
      __hip_atomic_fetch_add(fl, 1, __ATOMIC_RELAXED, __HIP_MEMORY_SCOPE_AGENT);
      while (__hip_atomic_load(fl, __ATOMIC_RELAXED, __HIP_MEMORY_SCOPE_AGENT) < CPG)
        __builtin_amdgcn_s_sleep(1);
    }
    __syncthreads();

    // stage full a[4][1024] into LDS via coherent atomic loads (lane-linear)
    {
      float tmp[16];
      #pragma unroll
      for (int j = 0; j < 16; ++j)
        tmp[j] = __hip_atomic_load(&apub_t[tid + 256 * j],
                                   __ATOMIC_RELAXED, __HIP_MEMORY_SCOPE_AGENT);
      #pragma unroll
      for (int j = 0; j < 16; ++j)
        a_lds[tid + 256 * j] = tmp[j];
    }
    __syncthreads();

    // stats per batch row (wave wv <-> row b=wv), ddof=1, eps on std
    {
      float s1 = 0.f, s2 = 0.f;
      #pragma unroll
      for (int i = 0; i < 16; ++i) {
        float v = a_lds[wv * HID + i * 64 + lane];
        s1 += v; s2 += v * v;
      }
      #pragma unroll
      for (int m = 1; m <= 32; m <<= 1) { s1 += __shfl_xor(s1, m); s2 += __shfl_xor(s2, m); }
      if (lane == 0) {
        float mean = s1 * (1.f / HID);
        float var = (s2 - (float)HID * mean * mean) * (1.f / (float)(HID - 1));
        stats_lds[wv][0] = mean;
        stats_lds[wv][1] = sqrtf(fmaxf(var, 0.f)) + EPS;
      }
    }
    __syncthreads();

    // h = relu(LN(a)) for rows k = tid + 256*j; write h_lds[k*4+b] (2-way: free)
    {
      float mean0 = stats_lds[0][0], rd0 = 1.f / stats_lds[0][1];
      float mean1 = stats_lds[1][0], rd1 = 1.f / stats_lds[1][1];
      float mean2 = stats_lds[2][0], rd2 = 1.f / stats_lds[2][1];
      float mean3 = stats_lds[3][0], rd3 = 1.f / stats_lds[3][1];
      #pragma unroll
      for (int j = 0; j < 4; ++j) {
        const int k = tid + 256 * j;
        float gk = g_lds[k], bk = be_lds[k];
        float h0 = fmaxf(gk * (a_lds[0 * HID + k] - mean0) * rd0 + bk, 0.f);
        float h1 = fmaxf(gk * (a_lds[1 * HID + k] - mean1) * rd1 + bk, 0.f);
        float h2 = fmaxf(gk * (a_lds[2 * HID + k] - mean2) * rd2 + bk, 0.f);
        float h3 = fmaxf(gk * (a_lds[3 * HID + k] - mean3) * rd3 + bk, 0.f);
        *(float4*)&h_lds[k * 4] = make_float4(h0, h1, h2, h3);
        if (c == 0) {
          h_all[((size_t)t * BATCH + g * BPG + 0) * HID + k] = h0;
          h_all[((size_t)t * BATCH + g * BPG + 1) * HID + k] = h1;
          h_all[((size_t)t * BATCH + g * BPG + 2) * HID + k] = h2;
          h_all[((size_t)t * BATCH + g * BPG + 3) * HID + k] = h3;
        }
      }
    }
    __syncthreads();
  }
}

// ---------------- softmax + loss/err per row ----------------
__global__ __launch_bounds__(256) void softmax_loss(
    float* __restrict__ out, const int* __restrict__ lab, float* __restrict__ acc) {
  __shared__ float rowbuf[NCLS];
  __shared__ float rv[4]; __shared__ int ri[4]; __shared__ float rs[4];
  __shared__ float shv[2];
  __shared__ int shidx;
  const int m = blockIdx.x;
  float* row = out + (size_t)m * NCLS;
  const int tid = threadIdx.x;
  const int lane = tid & 63, wid = tid >> 6;

  float vmax = -1e30f; int vidx = 0x7fffffff;
  for (int c = tid; c < NCLS; c += 256) {
    float v = row[c];
    rowbuf[c] = v;
    if (v > vmax) { vmax = v; vidx = c; }
  }
  #pragma unroll
  for (int off = 32; off; off >>= 1) {
    float ov = __shfl_down(vmax, off);
    int oi = __shfl_down(vidx, off);
    if (ov > vmax || (ov == vmax && oi < vidx)) { vmax = ov; vidx = oi; }
  }
  if (lane == 0) { rv[wid] = vmax; ri[wid] = vidx; }
  __syncthreads();
  if (tid == 0) {
    float bm = rv[0]; int bi = ri[0];
    for (int w = 1; w < 4; ++w)
      if (rv[w] > bm || (rv[w] == bm && ri[w] < bi)) { bm = rv[w]; bi = ri[w]; }
    shv[0] = bm; shidx = bi;
  }
  __syncthreads();
  float gmax = shv[0];
  float s = 0.f;
  for (int c = tid; c < NCLS; c += 256) s += expf(rowbuf[c] - gmax);
  #pragma unroll
  for (int off = 32; off; off >>= 1) s += __shfl_down(s, off);
  if (lane == 0) rs[wid] = s;
  __syncthreads();
  if (tid == 0) shv[1] = rs[0] + rs[1] + rs[2] + rs[3];
  __syncthreads();
  float lse = logf(shv[1]);
  for (int c = tid; c < NCLS; c += 256) row[c] = rowbuf[c] - gmax - lse;
  if (tid == 0) {
    int lb = lab[m];
    float nll = -(rowbuf[lb] - gmax - lse);
    atomicAdd(acc + 0, nll);
    atomicAdd(acc + 1, (shidx != lb) ? 1.f : 0.f);
  }
}

__global__ void init_acc(float* acc) { acc[threadIdx.x] = 0.f; }

__global__ void finalize_out(const float* __restrict__ acc, float* __restrict__ out) {
  out[0] = acc[0] * (1.f / (float)MROWS);
  out[1] = acc[1] * (1.f / (float)MROWS);
}

extern "C" void kernel_launch(void* const* d_in, const int* in_sizes, int n_in,
                              void* d_out, int out_size, void* d_ws, size_t ws_size,
                              hipStream_t stream) {
  const float* x     = (const float*)d_in[0];
  const int*   lab   = (const int*)d_in[1];
  const float* wx0_w = (const float*)d_in[3];
  const float* wx0_b = (const float*)d_in[4];
  const float* wx_w  = (const float*)d_in[5];
  const float* wx_b  = (const float*)d_in[6];
  const float* uh_w  = (const float*)d_in[7];
  const float* ln_g  = (const float*)d_in[8];
  const float* ln_b  = (const float*)d_in[9];
  const float* fco_w = (const float*)d_in[10];
  const float* fco_b = (const float*)d_in[11];
  float* out = (float*)d_out;

  float* wsf = (float*)d_ws;
  size_t off = 0;
  auto carve = [&](size_t n) { float* p = wsf + off; off += (n + 63) & ~(size_t)63; return p; };
  float* uhT   = carve((size_t)HID * HID);                 //  4 MB
  float* wxbuf = carve((size_t)MROWS * HID);               // 50 MB
  float* h_all = carve((size_t)MROWS * HID);               // 50 MB
  float* pre   = carve((size_t)MROWS * HID);               // 50 MB
  float* a_pub = carve((size_t)2 * NG * BPG * HID);        // 256 KB
  int*   flags = (int*)carve((size_t)4 * T_STEPS * NG);    // 51 KB
  float* acc   = carve(64);

  (void)hipMemsetAsync(flags, 0, (size_t)4 * T_STEPS * NG * sizeof(int), stream);
  init_acc<<<1, 2, 0, stream>>>(acc);

  for (int layer = 0; layer < 4; ++layer) {
    if (layer == 0) {
      gemm_nt<<<dim3(HID / BN, MROWS / BM), 256, 0, stream>>>(
          x, wx0_w, wx0_b, wxbuf, MROWS, HID, 440);
    } else {
      gemm_nt<<<dim3(HID / BN, MROWS / BM), 256, 0, stream>>>(
          h_all, wx_w + (size_t)(layer - 1) * HID * HID,
          wx_b + (size_t)(layer - 1) * HID, wxbuf, MROWS, HID, HID);
    }
    transpose1024<<<dim3(32, 32), dim3(32, 8), 0, stream>>>(
        uh_w + (size_t)layer * HID * HID, uhT);

    scan_layer<<<dim3(NG * CPG), 256, 0, stream>>>(
        wxbuf, uhT, h_all, pre, a_pub, flags + layer * T_STEPS * NG,
        ln_g + (size_t)layer * HID, ln_b + (size_t)layer * HID,
        (layer == 0) ? 1 : 0);
  }

  gemm_nt<<<dim3((NCLS + BN - 1) / BN, MROWS / BM), 256, 0, stream>>>(
      h_all, fco_w, fco_b, out + 2, MROWS, NCLS, HID);
  softmax_loss<<<MROWS, 256, 0, stream>>>(out + 2, lab, acc);
  finalize_out<<<1, 1, 0, stream>>>(acc, out);
}

// Round 5
// 15606.551 us; speedup vs baseline: 4.1277x; 1.1221x over previous
//
#include <hip/hip_runtime.h>
#include <math.h>

#define T_STEPS 400
#define BATCH   32
#define HID     1024
#define MROWS   (T_STEPS * BATCH)   // 12800
#define NCLS    3500
#define NG      8                    // batch groups
#define BPG     4                    // batch rows per group
#define CPG     32                   // blocks (column slices) per group
#define JS      32                   // columns per block
#define EPS     1e-6f
#define SLOTP   8                    // ints per progress slot (32B padding)

// ---------------- GEMM: C[M][N] = A[M][K] @ W[N][K]^T + bias[N] ----------------
#define BM 128
#define BN 128
#define BKQ 8

__global__ __launch_bounds__(256) void gemm_nt(
    const float* __restrict__ A, const float* __restrict__ W,
    const float* __restrict__ bias, float* __restrict__ C,
    int M, int N, int K) {
  __shared__ float As[BKQ][BM];
  __shared__ float Ws[BKQ][BN];
  const int tid = threadIdx.x;
  const int tx = tid & 15, ty = tid >> 4;
  const int m0 = blockIdx.y * BM, n0 = blockIdx.x * BN;
  const int ar = tid >> 1, aq = (tid & 1) * 4;

  float acc[8][8];
  #pragma unroll
  for (int i = 0; i < 8; ++i)
    #pragma unroll
    for (int j = 0; j < 8; ++j) acc[i][j] = 0.f;

  for (int k0 = 0; k0 < K; k0 += BKQ) {
    float4 av = *(const float4*)(A + (size_t)(m0 + ar) * K + k0 + aq);
    float4 wv = make_float4(0.f, 0.f, 0.f, 0.f);
    if (n0 + ar < N)
      wv = *(const float4*)(W + (size_t)(n0 + ar) * K + k0 + aq);
    __syncthreads();
    As[aq + 0][ar] = av.x; As[aq + 1][ar] = av.y;
    As[aq + 2][ar] = av.z; As[aq + 3][ar] = av.w;
    Ws[aq + 0][ar] = wv.x; Ws[aq + 1][ar] = wv.y;
    Ws[aq + 2][ar] = wv.z; Ws[aq + 3][ar] = wv.w;
    __syncthreads();
    #pragma unroll
    for (int k = 0; k < BKQ; ++k) {
      float a8[8], w8[8];
      *(float4*)&a8[0] = *(const float4*)&As[k][ty * 8];
      *(float4*)&a8[4] = *(const float4*)&As[k][ty * 8 + 4];
      *(float4*)&w8[0] = *(const float4*)&Ws[k][tx * 8];
      *(float4*)&w8[4] = *(const float4*)&Ws[k][tx * 8 + 4];
      #pragma unroll
      for (int i = 0; i < 8; ++i)
        #pragma unroll
        for (int j = 0; j < 8; ++j)
          acc[i][j] += a8[i] * w8[j];
    }
  }
  #pragma unroll
  for (int i = 0; i < 8; ++i) {
    int row = m0 + ty * 8 + i;
    #pragma unroll
    for (int j = 0; j < 8; ++j) {
      int col = n0 + tx * 8 + j;
      if (col < N)
        C[(size_t)row * N + col] = acc[i][j] + bias[col];
    }
  }
}

// ---------------- transpose 1024x1024: out[k][j] = in[j][k] ----------------
__global__ void transpose1024(const float* __restrict__ in, float* __restrict__ out) {
  __shared__ float tile[32][33];
  const int bx = blockIdx.x * 32, by = blockIdx.y * 32;
  const int tx = threadIdx.x, ty = threadIdx.y;  // 32 x 8
  #pragma unroll
  for (int i = 0; i < 32; i += 8)
    tile[ty + i][tx] = in[(size_t)(by + ty + i) * HID + bx + tx];
  __syncthreads();
  #pragma unroll
  for (int i = 0; i < 32; i += 8)
    out[(size_t)(bx + ty + i) * HID + by + tx] = tile[tx][ty + i];
}

// ---------------- scan: per-block progress slots (no RMW), IF-coherent atomics ----------------
// grid = 256 blocks x 256 thr. group g = blk>>5 owns batch rows [4g,4g+4);
// block c = blk&31 owns columns [32c, 32c+32).
// matvec thread map: jw = tid&3 (8-col octet), ks = tid>>2; thread's k-rows = ks + 64*i.
// sync: block stores t+1 to prog[g][c] (32B-padded slot); wave0 lanes poll all 32 slots.
__global__ __launch_bounds__(256, 1) void scan_layer(
    const float* __restrict__ wx, const float* __restrict__ uhT,
    float* __restrict__ h_all, float* __restrict__ pre_all,
    float* __restrict__ a_pub,        // [2][NG][BPG][HID]
    int* __restrict__ prog,           // [NG][CPG][SLOTP]
    const float* __restrict__ gamma, const float* __restrict__ beta,
    int skip_sub) {
  const int tid  = threadIdx.x;
  const int g    = blockIdx.x >> 5;
  const int c    = blockIdx.x & 31;
  const int lane = tid & 63;
  const int wv   = tid >> 6;          // wave 0..3
  const int jw   = tid & 3;
  const int ks   = tid >> 2;          // 0..63
  const int col0 = c * JS + jw * 8;

  int* prog_g = prog + (size_t)g * CPG * SLOTP;

  __shared__ float h_lds[HID * BPG];      // flat [k*4+b], 16KB
  __shared__ float a_lds[BPG * HID];      // flat [b*1024+k], 16KB
  __shared__ float partial[4][BPG][JS];   // per-wave partials, 2KB
  __shared__ float stats_lds[BPG][2];
  __shared__ float g_lds[HID], be_lds[HID];

  for (int k = tid; k < HID; k += 256) { g_lds[k] = gamma[k]; be_lds[k] = beta[k]; }

  // persistent Uh slice in registers: rows ks+64i, cols col0..col0+7
  float4 u0[16], u1[16];
  #pragma unroll
  for (int i = 0; i < 16; ++i) {
    const float* p = uhT + (size_t)(ks + 64 * i) * HID + col0;
    u0[i] = *(const float4*)p;
    u1[i] = *(const float4*)(p + 4);
  }
  __syncthreads();

  for (int t = 0; t < T_STEPS; ++t) {
    const int par = t & 1;
    float* apub_t = a_pub + ((size_t)par * NG + g) * (BPG * HID);

    // issue wx / pre loads early (independent of h)
    float at0 = 0.f, pre_old = 0.f;
    size_t gidx = 0;
    if (tid < 128) {
      const int b = tid >> 5, j = tid & 31;
      gidx = ((size_t)t * BATCH + g * BPG + b) * HID + c * JS + j;
      at0 = wx[gidx];
      pre_old = skip_sub ? 0.f : pre_all[gidx];
    }

    if (t > 0) {
      float pacc[4][8];
      #pragma unroll
      for (int b = 0; b < 4; ++b)
        #pragma unroll
        for (int q = 0; q < 8; ++q) pacc[b][q] = 0.f;
      #pragma unroll
      for (int i = 0; i < 16; ++i) {
        float4 h4 = *(const float4*)&h_lds[(ks + 64 * i) * 4];  // 2-way: free
        #pragma unroll
        for (int b = 0; b < 4; ++b) {
          float hb = ((const float*)&h4)[b];
          pacc[b][0] += hb * u0[i].x; pacc[b][1] += hb * u0[i].y;
          pacc[b][2] += hb * u0[i].z; pacc[b][3] += hb * u0[i].w;
          pacc[b][4] += hb * u1[i].x; pacc[b][5] += hb * u1[i].y;
          pacc[b][6] += hb * u1[i].z; pacc[b][7] += hb * u1[i].w;
        }
      }
      // reduce 16 k-strips within wave (lane bits 2..5)
      #pragma unroll
      for (int b = 0; b < 4; ++b)
        #pragma unroll
        for (int q = 0; q < 8; ++q) {
          float v = pacc[b][q];
          v += __shfl_xor(v, 4);
          v += __shfl_xor(v, 8);
          v += __shfl_xor(v, 16);
          v += __shfl_xor(v, 32);
          pacc[b][q] = v;
        }
      if ((lane >> 2) == 0) {   // lanes 0..3, one per jw
        #pragma unroll
        for (int b = 0; b < 4; ++b) {
          *(float4*)&partial[wv][b][jw * 8]     = *(const float4*)&pacc[b][0];
          *(float4*)&partial[wv][b][jw * 8 + 4] = *(const float4*)&pacc[b][4];
        }
      }
    }
    __syncthreads();

    // finalize a-slice; publish via IF-coherent relaxed atomic stores (no fence)
    if (tid < 128) {
      const int b = tid >> 5, j = tid & 31;
      float red = 0.f;
      if (t > 0)
        red = partial[0][b][j] + partial[1][b][j] + partial[2][b][j] + partial[3][b][j];
      float at = at0 + red;
      pre_all[gidx] = at;
      __hip_atomic_store(&apub_t[(size_t)b * HID + c * JS + j], at - pre_old,
                         __ATOMIC_RELAXED, __HIP_MEMORY_SCOPE_AGENT);
    }
    // each thread drains its own outstanding stores before the barrier
    asm volatile("s_waitcnt vmcnt(0)" ::: "memory");
    __syncthreads();

    // announce: store step number to own slot (no RMW, no contention)
    if (tid == 0)
      __hip_atomic_store(&prog_g[c * SLOTP], t + 1,
                         __ATOMIC_RELAXED, __HIP_MEMORY_SCOPE_AGENT);
    // wave 0: each lane polls one of the 32 slots until all reached t+1
    if (wv == 0) {
      const int* p = &prog_g[(lane & 31) * SLOTP];
      while (true) {
        int v = __hip_atomic_load(p, __ATOMIC_RELAXED, __HIP_MEMORY_SCOPE_AGENT);
        if (__all(v >= t + 1)) break;
        __builtin_amdgcn_s_sleep(1);
      }
    }
    __syncthreads();

    // stage full a[4][1024] into LDS via coherent atomic loads (lane-linear)
    {
      float tmp[16];
      #pragma unroll
      for (int j = 0; j < 16; ++j)
        tmp[j] = __hip_atomic_load(&apub_t[tid + 256 * j],
                                   __ATOMIC_RELAXED, __HIP_MEMORY_SCOPE_AGENT);
      #pragma unroll
      for (int j = 0; j < 16; ++j)
        a_lds[tid + 256 * j] = tmp[j];
    }
    __syncthreads();

    // stats per batch row (wave wv <-> row b=wv), ddof=1, eps on std
    {
      float s1 = 0.f, s2 = 0.f;
      #pragma unroll
      for (int i = 0; i < 16; ++i) {
        float v = a_lds[wv * HID + i * 64 + lane];
        s1 += v; s2 += v * v;
      }
      #pragma unroll
      for (int m = 1; m <= 32; m <<= 1) { s1 += __shfl_xor(s1, m); s2 += __shfl_xor(s2, m); }
      if (lane == 0) {
        float mean = s1 * (1.f / HID);
        float var = (s2 - (float)HID * mean * mean) * (1.f / (float)(HID - 1));
        stats_lds[wv][0] = mean;
        stats_lds[wv][1] = sqrtf(fmaxf(var, 0.f)) + EPS;
      }
    }
    __syncthreads();

    // h = relu(LN(a)) for rows k = tid + 256*j; write h_lds[k*4+b] (2-way: free)
    {
      float mean0 = stats_lds[0][0], rd0 = 1.f / stats_lds[0][1];
      float mean1 = stats_lds[1][0], rd1 = 1.f / stats_lds[1][1];
      float mean2 = stats_lds[2][0], rd2 = 1.f / stats_lds[2][1];
      float mean3 = stats_lds[3][0], rd3 = 1.f / stats_lds[3][1];
      #pragma unroll
      for (int j = 0; j < 4; ++j) {
        const int k = tid + 256 * j;
        float gk = g_lds[k], bk = be_lds[k];
        float h0 = fmaxf(gk * (a_lds[0 * HID + k] - mean0) * rd0 + bk, 0.f);
        float h1 = fmaxf(gk * (a_lds[1 * HID + k] - mean1) * rd1 + bk, 0.f);
        float h2 = fmaxf(gk * (a_lds[2 * HID + k] - mean2) * rd2 + bk, 0.f);
        float h3 = fmaxf(gk * (a_lds[3 * HID + k] - mean3) * rd3 + bk, 0.f);
        *(float4*)&h_lds[k * 4] = make_float4(h0, h1, h2, h3);
        if (c == 0) {
          h_all[((size_t)t * BATCH + g * BPG + 0) * HID + k] = h0;
          h_all[((size_t)t * BATCH + g * BPG + 1) * HID + k] = h1;
          h_all[((size_t)t * BATCH + g * BPG + 2) * HID + k] = h2;
          h_all[((size_t)t * BATCH + g * BPG + 3) * HID + k] = h3;
        }
      }
    }
    __syncthreads();
  }
}

// ---------------- softmax + loss/err per row ----------------
__global__ __launch_bounds__(256) void softmax_loss(
    float* __restrict__ out, const int* __restrict__ lab, float* __restrict__ acc) {
  __shared__ float rowbuf[NCLS];
  __shared__ float rv[4]; __shared__ int ri[4]; __shared__ float rs[4];
  __shared__ float shv[2];
  __shared__ int shidx;
  const int m = blockIdx.x;
  float* row = out + (size_t)m * NCLS;
  const int tid = threadIdx.x;
  const int lane = tid & 63, wid = tid >> 6;

  float vmax = -1e30f; int vidx = 0x7fffffff;
  for (int c = tid; c < NCLS; c += 256) {
    float v = row[c];
    rowbuf[c] = v;
    if (v > vmax) { vmax = v; vidx = c; }
  }
  #pragma unroll
  for (int off = 32; off; off >>= 1) {
    float ov = __shfl_down(vmax, off);
    int oi = __shfl_down(vidx, off);
    if (ov > vmax || (ov == vmax && oi < vidx)) { vmax = ov; vidx = oi; }
  }
  if (lane == 0) { rv[wid] = vmax; ri[wid] = vidx; }
  __syncthreads();
  if (tid == 0) {
    float bm = rv[0]; int bi = ri[0];
    for (int w = 1; w < 4; ++w)
      if (rv[w] > bm || (rv[w] == bm && ri[w] < bi)) { bm = rv[w]; bi = ri[w]; }
    shv[0] = bm; shidx = bi;
  }
  __syncthreads();
  float gmax = shv[0];
  float s = 0.f;
  for (int c = tid; c < NCLS; c += 256) s += expf(rowbuf[c] - gmax);
  #pragma unroll
  for (int off = 32; off; off >>= 1) s += __shfl_down(s, off);
  if (lane == 0) rs[wid] = s;
  __syncthreads();
  if (tid == 0) shv[1] = rs[0] + rs[1] + rs[2] + rs[3];
  __syncthreads();
  float lse = logf(shv[1]);
  for (int c = tid; c < NCLS; c += 256) row[c] = rowbuf[c] - gmax - lse;
  if (tid == 0) {
    int lb = lab[m];
    float nll = -(rowbuf[lb] - gmax - lse);
    atomicAdd(acc + 0, nll);
    atomicAdd(acc + 1, (shidx != lb) ? 1.f : 0.f);
  }
}

__global__ void init_acc(float* acc) { acc[threadIdx.x] = 0.f; }

__global__ void finalize_out(const float* __restrict__ acc, float* __restrict__ out) {
  out[0] = acc[0] * (1.f / (float)MROWS);
  out[1] = acc[1] * (1.f / (float)MROWS);
}

extern "C" void kernel_launch(void* const* d_in, const int* in_sizes, int n_in,
                              void* d_out, int out_size, void* d_ws, size_t ws_size,
                              hipStream_t stream) {
  const float* x     = (const float*)d_in[0];
  const int*   lab   = (const int*)d_in[1];
  const float* wx0_w = (const float*)d_in[3];
  const float* wx0_b = (const float*)d_in[4];
  const float* wx_w  = (const float*)d_in[5];
  const float* wx_b  = (const float*)d_in[6];
  const float* uh_w  = (const float*)d_in[7];
  const float* ln_g  = (const float*)d_in[8];
  const float* ln_b  = (const float*)d_in[9];
  const float* fco_w = (const float*)d_in[10];
  const float* fco_b = (const float*)d_in[11];
  float* out = (float*)d_out;

  float* wsf = (float*)d_ws;
  size_t off = 0;
  auto carve = [&](size_t n) { float* p = wsf + off; off += (n + 63) & ~(size_t)63; return p; };
  float* uhT   = carve((size_t)HID * HID);                 //  4 MB
  float* wxbuf = carve((size_t)MROWS * HID);               // 50 MB
  float* h_all = carve((size_t)MROWS * HID);               // 50 MB
  float* pre   = carve((size_t)MROWS * HID);               // 50 MB
  float* a_pub = carve((size_t)2 * NG * BPG * HID);        // 256 KB
  int*   prog  = (int*)carve((size_t)4 * NG * CPG * SLOTP); // 32 KB (4 layers)
  float* acc   = carve(64);

  (void)hipMemsetAsync(prog, 0, (size_t)4 * NG * CPG * SLOTP * sizeof(int), stream);
  init_acc<<<1, 2, 0, stream>>>(acc);

  for (int layer = 0; layer < 4; ++layer) {
    if (layer == 0) {
      gemm_nt<<<dim3(HID / BN, MROWS / BM), 256, 0, stream>>>(
          x, wx0_w, wx0_b, wxbuf, MROWS, HID, 440);
    } else {
      gemm_nt<<<dim3(HID / BN, MROWS / BM), 256, 0, stream>>>(
          h_all, wx_w + (size_t)(layer - 1) * HID * HID,
          wx_b + (size_t)(layer - 1) * HID, wxbuf, MROWS, HID, HID);
    }
    transpose1024<<<dim3(32, 32), dim3(32, 8), 0, stream>>>(
        uh_w + (size_t)layer * HID * HID, uhT);

    scan_layer<<<dim3(NG * CPG), 256, 0, stream>>>(
        wxbuf, uhT, h_all, pre, a_pub, prog + (size_t)layer * NG * CPG * SLOTP,
        ln_g + (size_t)layer * HID, ln_b + (size_t)layer * HID,
        (layer == 0) ? 1 : 0);
  }

  gemm_nt<<<dim3((NCLS + BN - 1) / BN, MROWS / BM), 256, 0, stream>>>(
      h_all, fco_w, fco_b, out + 2, MROWS, NCLS, HID);
  softmax_loss<<<MROWS, 256, 0, stream>>>(out + 2, lab, acc);
  finalize_out<<<1, 1, 0, stream>>>(acc, out);
}

// Round 6
// 10060.595 us; speedup vs baseline: 6.4031x; 1.5513x over previous
//
#include <hip/hip_runtime.h>
#include <math.h>

#define T_STEPS 400
#define BATCH   32
#define HID     1024
#define MROWS   (T_STEPS * BATCH)   // 12800
#define NCLS    3500
#define NG      8                    // batch groups
#define BPG     4                    // batch rows per group
#define CPG     32                   // blocks (column slices) per group
#define JS      32                   // columns per block
#define EPS     1e-6f
#define SLOTP   8                    // ints per progress slot (32B padding)

typedef __attribute__((ext_vector_type(8))) short short8v;   // 8 bf16 (4 VGPR)
typedef __attribute__((ext_vector_type(4))) float f32x4;

__device__ __forceinline__ unsigned short bf16_rne(float x) {
  unsigned u = __builtin_bit_cast(unsigned, x);
  unsigned r = u + 0x7FFFu + ((u >> 16) & 1u);
  return (unsigned short)(r >> 16);
}

// stage a 128x32 fp32 tile into hi/lo bf16 LDS tiles (chunk-XOR swizzled).
// rows >= rowlim or k >= K are zero-filled.
__device__ __forceinline__ void stage_tile(
    const float* __restrict__ src, int rowlim, int row0, int ld,
    int k0, int K, unsigned short* hi, unsigned short* lo, int tid) {
  #pragma unroll
  for (int it = 0; it < 2; ++it) {
    const int task = tid + 256 * it;          // 512 tasks: 128 rows x 4 chunks
    const int r = task >> 2, q = task & 3;
    const int gr = row0 + r;
    const bool rok = gr < rowlim;
    const float* p = src + (size_t)gr * ld + k0 + q * 8;
    float x[8];
    if (rok && (k0 + 32 <= K)) {
      float4 v0 = *(const float4*)p;
      float4 v1 = *(const float4*)(p + 4);
      x[0] = v0.x; x[1] = v0.y; x[2] = v0.z; x[3] = v0.w;
      x[4] = v1.x; x[5] = v1.y; x[6] = v1.z; x[7] = v1.w;
    } else {
      #pragma unroll
      for (int j = 0; j < 8; ++j)
        x[j] = (rok && (k0 + q * 8 + j) < K) ? p[j] : 0.f;
    }
    unsigned hp[4], lp[4];
    #pragma unroll
    for (int j = 0; j < 4; ++j) {
      unsigned short h0 = bf16_rne(x[2 * j]), h1 = bf16_rne(x[2 * j + 1]);
      float f0 = __builtin_bit_cast(float, (unsigned)h0 << 16);
      float f1 = __builtin_bit_cast(float, (unsigned)h1 << 16);
      unsigned short l0 = bf16_rne(x[2 * j] - f0), l1 = bf16_rne(x[2 * j + 1] - f1);
      hp[j] = (unsigned)h0 | ((unsigned)h1 << 16);
      lp[j] = (unsigned)l0 | ((unsigned)l1 << 16);
    }
    const int idx = (r * 4 + (q ^ (r & 3))) * 8;   // 16B-chunk swizzle
    *(uint4*)&hi[idx] = make_uint4(hp[0], hp[1], hp[2], hp[3]);
    *(uint4*)&lo[idx] = make_uint4(lp[0], lp[1], lp[2], lp[3]);
  }
}

// ---------------- MFMA GEMM: C[M][N] = A[M][K] @ W[N][K]^T + bias[N] ----------------
// NPASS=3: split-bf16 (hi*hi + lo*hi + hi*lo) ~ fp32 accuracy. NPASS=1: plain bf16.
// 128x128 tile, 4 waves, each wave: 8 m-frags x 2 n-frags of 16x16x32 MFMA.
template <int NPASS>
__global__ __launch_bounds__(256) void gemm_mfma(
    const float* __restrict__ A, const float* __restrict__ W,
    const float* __restrict__ bias, float* __restrict__ C,
    int M, int N, int K) {
  __shared__ unsigned short Ah[128 * 32], Al[128 * 32];
  __shared__ unsigned short Bh[128 * 32], Bl[128 * 32];
  const int tid = threadIdx.x;
  const int m0 = blockIdx.y * 128, n0 = blockIdx.x * 128;
  const int w = tid >> 6, lane = tid & 63;
  const int rlow = lane & 15, ksel = lane >> 4;

  f32x4 acc[8][2];
  #pragma unroll
  for (int i = 0; i < 8; ++i) {
    acc[i][0] = (f32x4)(0.f);
    acc[i][1] = (f32x4)(0.f);
  }

  for (int k0 = 0; k0 < K; k0 += 32) {
    __syncthreads();
    stage_tile(A, M, m0, K, k0, K, Ah, Al, tid);
    stage_tile(W, N, n0, K, k0, K, Bh, Bl, tid);
    __syncthreads();

    short8v wh[2], wl[2];
    #pragma unroll
    for (int nf = 0; nf < 2; ++nf) {
      const int rn = w * 32 + nf * 16 + rlow;
      const int idx = (rn * 4 + (ksel ^ (rn & 3))) * 8;
      wh[nf] = *(const short8v*)&Bh[idx];
      if (NPASS == 3) wl[nf] = *(const short8v*)&Bl[idx];
    }
    #pragma unroll
    for (int i = 0; i < 8; ++i) {
      const int ra = i * 16 + rlow;
      const int idx = (ra * 4 + (ksel ^ (ra & 3))) * 8;
      short8v ah = *(const short8v*)&Ah[idx];
      if (NPASS == 3) {
        short8v al = *(const short8v*)&Al[idx];
        acc[i][0] = __builtin_amdgcn_mfma_f32_16x16x32_bf16(ah, wh[0], acc[i][0], 0, 0, 0);
        acc[i][0] = __builtin_amdgcn_mfma_f32_16x16x32_bf16(al, wh[0], acc[i][0], 0, 0, 0);
        acc[i][0] = __builtin_amdgcn_mfma_f32_16x16x32_bf16(ah, wl[0], acc[i][0], 0, 0, 0);
        acc[i][1] = __builtin_amdgcn_mfma_f32_16x16x32_bf16(ah, wh[1], acc[i][1], 0, 0, 0);
        acc[i][1] = __builtin_amdgcn_mfma_f32_16x16x32_bf16(al, wh[1], acc[i][1], 0, 0, 0);
        acc[i][1] = __builtin_amdgcn_mfma_f32_16x16x32_bf16(ah, wl[1], acc[i][1], 0, 0, 0);
      } else {
        acc[i][0] = __builtin_amdgcn_mfma_f32_16x16x32_bf16(ah, wh[0], acc[i][0], 0, 0, 0);
        acc[i][1] = __builtin_amdgcn_mfma_f32_16x16x32_bf16(ah, wh[1], acc[i][1], 0, 0, 0);
      }
    }
  }

  // epilogue: D row = m0+i*16+ksel*4+reg, col = n0+w*32+nf*16+rlow  [m89 mapping]
  int col[2]; float bb[2]; bool cok[2];
  #pragma unroll
  for (int nf = 0; nf < 2; ++nf) {
    col[nf] = n0 + w * 32 + nf * 16 + rlow;
    cok[nf] = col[nf] < N;
    bb[nf] = cok[nf] ? bias[col[nf]] : 0.f;
  }
  #pragma unroll
  for (int i = 0; i < 8; ++i) {
    const int row = m0 + i * 16 + ksel * 4;
    #pragma unroll
    for (int nf = 0; nf < 2; ++nf) {
      if (cok[nf]) {
        float* cp = C + (size_t)row * N + col[nf];
        cp[0 * N] = acc[i][nf][0] + bb[nf];
        cp[1 * N] = acc[i][nf][1] + bb[nf];
        cp[2 * N] = acc[i][nf][2] + bb[nf];
        cp[3 * N] = acc[i][nf][3] + bb[nf];
      }
    }
  }
}

// ---------------- transpose 1024x1024: out[k][j] = in[j][k] ----------------
__global__ void transpose1024(const float* __restrict__ in, float* __restrict__ out) {
  __shared__ float tile[32][33];
  const int bx = blockIdx.x * 32, by = blockIdx.y * 32;
  const int tx = threadIdx.x, ty = threadIdx.y;  // 32 x 8
  #pragma unroll
  for (int i = 0; i < 32; i += 8)
    tile[ty + i][tx] = in[(size_t)(by + ty + i) * HID + bx + tx];
  __syncthreads();
  #pragma unroll
  for (int i = 0; i < 32; i += 8)
    out[(size_t)(bx + ty + i) * HID + by + tx] = tile[tx][ty + i];
}

// ---------------- scan: per-block progress slots (no RMW), IF-coherent atomics ----------------
__global__ __launch_bounds__(256, 1) void scan_layer(
    const float* __restrict__ wx, const float* __restrict__ uhT,
    float* __restrict__ h_all, float* __restrict__ pre_all,
    float* __restrict__ a_pub,        // [2][NG][BPG][HID]
    int* __restrict__ prog,           // [NG][CPG][SLOTP]
    const float* __restrict__ gamma, const float* __restrict__ beta,
    int skip_sub) {
  const int tid  = threadIdx.x;
  const int g    = blockIdx.x >> 5;
  const int c    = blockIdx.x & 31;
  const int lane = tid & 63;
  const int wv   = tid >> 6;          // wave 0..3
  const int jw   = tid & 3;
  const int ks   = tid >> 2;          // 0..63
  const int col0 = c * JS + jw * 8;

  int* prog_g = prog + (size_t)g * CPG * SLOTP;

  __shared__ float h_lds[HID * BPG];      // flat [k*4+b], 16KB
  __shared__ float a_lds[BPG * HID];      // flat [b*1024+k], 16KB
  __shared__ float partial[4][BPG][JS];   // per-wave partials, 2KB
  __shared__ float stats_lds[BPG][2];
  __shared__ float g_lds[HID], be_lds[HID];

  for (int k = tid; k < HID; k += 256) { g_lds[k] = gamma[k]; be_lds[k] = beta[k]; }

  // persistent Uh slice in registers: rows ks+64i, cols col0..col0+7
  float4 u0[16], u1[16];
  #pragma unroll
  for (int i = 0; i < 16; ++i) {
    const float* p = uhT + (size_t)(ks + 64 * i) * HID + col0;
    u0[i] = *(const float4*)p;
    u1[i] = *(const float4*)(p + 4);
  }
  __syncthreads();

  for (int t = 0; t < T_STEPS; ++t) {
    const int par = t & 1;
    float* apub_t = a_pub + ((size_t)par * NG + g) * (BPG * HID);

    // issue wx / pre loads early (independent of h)
    float at0 = 0.f, pre_old = 0.f;
    size_t gidx = 0;
    if (tid < 128) {
      const int b = tid >> 5, j = tid & 31;
      gidx = ((size_t)t * BATCH + g * BPG + b) * HID + c * JS + j;
      at0 = wx[gidx];
      pre_old = skip_sub ? 0.f : pre_all[gidx];
    }

    if (t > 0) {
      float pacc[4][8];
      #pragma unroll
      for (int b = 0; b < 4; ++b)
        #pragma unroll
        for (int q = 0; q < 8; ++q) pacc[b][q] = 0.f;
      #pragma unroll
      for (int i = 0; i < 16; ++i) {
        float4 h4 = *(const float4*)&h_lds[(ks + 64 * i) * 4];  // 2-way: free
        #pragma unroll
        for (int b = 0; b < 4; ++b) {
          float hb = ((const float*)&h4)[b];
          pacc[b][0] += hb * u0[i].x; pacc[b][1] += hb * u0[i].y;
          pacc[b][2] += hb * u0[i].z; pacc[b][3] += hb * u0[i].w;
          pacc[b][4] += hb * u1[i].x; pacc[b][5] += hb * u1[i].y;
          pacc[b][6] += hb * u1[i].z; pacc[b][7] += hb * u1[i].w;
        }
      }
      #pragma unroll
      for (int b = 0; b < 4; ++b)
        #pragma unroll
        for (int q = 0; q < 8; ++q) {
          float v = pacc[b][q];
          v += __shfl_xor(v, 4);
          v += __shfl_xor(v, 8);
          v += __shfl_xor(v, 16);
          v += __shfl_xor(v, 32);
          pacc[b][q] = v;
        }
      if ((lane >> 2) == 0) {   // lanes 0..3, one per jw
        #pragma unroll
        for (int b = 0; b < 4; ++b) {
          *(float4*)&partial[wv][b][jw * 8]     = *(const float4*)&pacc[b][0];
          *(float4*)&partial[wv][b][jw * 8 + 4] = *(const float4*)&pacc[b][4];
        }
      }
    }
    __syncthreads();

    // finalize a-slice; publish via IF-coherent relaxed atomic stores (no fence)
    if (tid < 128) {
      const int b = tid >> 5, j = tid & 31;
      float red = 0.f;
      if (t > 0)
        red = partial[0][b][j] + partial[1][b][j] + partial[2][b][j] + partial[3][b][j];
      float at = at0 + red;
      pre_all[gidx] = at;
      __hip_atomic_store(&apub_t[(size_t)b * HID + c * JS + j], at - pre_old,
                         __ATOMIC_RELAXED, __HIP_MEMORY_SCOPE_AGENT);
    }
    asm volatile("s_waitcnt vmcnt(0)" ::: "memory");
    __syncthreads();

    if (tid == 0)
      __hip_atomic_store(&prog_g[c * SLOTP], t + 1,
                         __ATOMIC_RELAXED, __HIP_MEMORY_SCOPE_AGENT);
    if (wv == 0) {
      const int* p = &prog_g[(lane & 31) * SLOTP];
      while (true) {
        int v = __hip_atomic_load(p, __ATOMIC_RELAXED, __HIP_MEMORY_SCOPE_AGENT);
        if (__all(v >= t + 1)) break;
        __builtin_amdgcn_s_sleep(1);
      }
    }
    __syncthreads();

    // stage full a[4][1024] into LDS via coherent atomic loads (lane-linear)
    {
      float tmp[16];
      #pragma unroll
      for (int j = 0; j < 16; ++j)
        tmp[j] = __hip_atomic_load(&apub_t[tid + 256 * j],
                                   __ATOMIC_RELAXED, __HIP_MEMORY_SCOPE_AGENT);
      #pragma unroll
      for (int j = 0; j < 16; ++j)
        a_lds[tid + 256 * j] = tmp[j];
    }
    __syncthreads();

    // stats per batch row (wave wv <-> row b=wv), ddof=1, eps on std
    {
      float s1 = 0.f, s2 = 0.f;
      #pragma unroll
      for (int i = 0; i < 16; ++i) {
        float v = a_lds[wv * HID + i * 64 + lane];
        s1 += v; s2 += v * v;
      }
      #pragma unroll
      for (int m = 1; m <= 32; m <<= 1) { s1 += __shfl_xor(s1, m); s2 += __shfl_xor(s2, m); }
      if (lane == 0) {
        float mean = s1 * (1.f / HID);
        float var = (s2 - (float)HID * mean * mean) * (1.f / (float)(HID - 1));
        stats_lds[wv][0] = mean;
        stats_lds[wv][1] = sqrtf(fmaxf(var, 0.f)) + EPS;
      }
    }
    __syncthreads();

    // h = relu(LN(a)) for rows k = tid + 256*j; write h_lds[k*4+b] (2-way: free)
    {
      float mean0 = stats_lds[0][0], rd0 = 1.f / stats_lds[0][1];
      float mean1 = stats_lds[1][0], rd1 = 1.f / stats_lds[1][1];
      float mean2 = stats_lds[2][0], rd2 = 1.f / stats_lds[2][1];
      float mean3 = stats_lds[3][0], rd3 = 1.f / stats_lds[3][1];
      #pragma unroll
      for (int j = 0; j < 4; ++j) {
        const int k = tid + 256 * j;
        float gk = g_lds[k], bk = be_lds[k];
        float h0 = fmaxf(gk * (a_lds[0 * HID + k] - mean0) * rd0 + bk, 0.f);
        float h1 = fmaxf(gk * (a_lds[1 * HID + k] - mean1) * rd1 + bk, 0.f);
        float h2 = fmaxf(gk * (a_lds[2 * HID + k] - mean2) * rd2 + bk, 0.f);
        float h3 = fmaxf(gk * (a_lds[3 * HID + k] - mean3) * rd3 + bk, 0.f);
        *(float4*)&h_lds[k * 4] = make_float4(h0, h1, h2, h3);
        if (c == 0) {
          h_all[((size_t)t * BATCH + g * BPG + 0) * HID + k] = h0;
          h_all[((size_t)t * BATCH + g * BPG + 1) * HID + k] = h1;
          h_all[((size_t)t * BATCH + g * BPG + 2) * HID + k] = h2;
          h_all[((size_t)t * BATCH + g * BPG + 3) * HID + k] = h3;
        }
      }
    }
    __syncthreads();
  }
}

// ---------------- softmax + loss/err per row ----------------
__global__ __launch_bounds__(256) void softmax_loss(
    float* __restrict__ out, const int* __restrict__ lab, float* __restrict__ acc) {
  __shared__ float rowbuf[NCLS];
  __shared__ float rv[4]; __shared__ int ri[4]; __shared__ float rs[4];
  __shared__ float shv[2];
  __shared__ int shidx;
  const int m = blockIdx.x;
  float* row = out + (size_t)m * NCLS;
  const int tid = threadIdx.x;
  const int lane = tid & 63, wid = tid >> 6;

  float vmax = -1e30f; int vidx = 0x7fffffff;
  for (int c = tid; c < NCLS; c += 256) {
    float v = row[c];
    rowbuf[c] = v;
    if (v > vmax) { vmax = v; vidx = c; }
  }
  #pragma unroll
  for (int off = 32; off; off >>= 1) {
    float ov = __shfl_down(vmax, off);
    int oi = __shfl_down(vidx, off);
    if (ov > vmax || (ov == vmax && oi < vidx)) { vmax = ov; vidx = oi; }
  }
  if (lane == 0) { rv[wid] = vmax; ri[wid] = vidx; }
  __syncthreads();
  if (tid == 0) {
    float bm = rv[0]; int bi = ri[0];
    for (int w = 1; w < 4; ++w)
      if (rv[w] > bm || (rv[w] == bm && ri[w] < bi)) { bm = rv[w]; bi = ri[w]; }
    shv[0] = bm; shidx = bi;
  }
  __syncthreads();
  float gmax = shv[0];
  float s = 0.f;
  for (int c = tid; c < NCLS; c += 256) s += expf(rowbuf[c] - gmax);
  #pragma unroll
  for (int off = 32; off; off >>= 1) s += __shfl_down(s, off);
  if (lane == 0) rs[wid] = s;
  __syncthreads();
  if (tid == 0) shv[1] = rs[0] + rs[1] + rs[2] + rs[3];
  __syncthreads();
  float lse = logf(shv[1]);
  for (int c = tid; c < NCLS; c += 256) row[c] = rowbuf[c] - gmax - lse;
  if (tid == 0) {
    int lb = lab[m];
    float nll = -(rowbuf[lb] - gmax - lse);
    atomicAdd(acc + 0, nll);
    atomicAdd(acc + 1, (shidx != lb) ? 1.f : 0.f);
  }
}

__global__ void init_acc(float* acc) { acc[threadIdx.x] = 0.f; }

__global__ void finalize_out(const float* __restrict__ acc, float* __restrict__ out) {
  out[0] = acc[0] * (1.f / (float)MROWS);
  out[1] = acc[1] * (1.f / (float)MROWS);
}

extern "C" void kernel_launch(void* const* d_in, const int* in_sizes, int n_in,
                              void* d_out, int out_size, void* d_ws, size_t ws_size,
                              hipStream_t stream) {
  const float* x     = (const float*)d_in[0];
  const int*   lab   = (const int*)d_in[1];
  const float* wx0_w = (const float*)d_in[3];
  const float* wx0_b = (const float*)d_in[4];
  const float* wx_w  = (const float*)d_in[5];
  const float* wx_b  = (const float*)d_in[6];
  const float* uh_w  = (const float*)d_in[7];
  const float* ln_g  = (const float*)d_in[8];
  const float* ln_b  = (const float*)d_in[9];
  const float* fco_w = (const float*)d_in[10];
  const float* fco_b = (const float*)d_in[11];
  float* out = (float*)d_out;

  float* wsf = (float*)d_ws;
  size_t off = 0;
  auto carve = [&](size_t n) { float* p = wsf + off; off += (n + 63) & ~(size_t)63; return p; };
  float* uhT   = carve((size_t)HID * HID);                 //  4 MB
  float* wxbuf = carve((size_t)MROWS * HID);               // 50 MB
  float* h_all = carve((size_t)MROWS * HID);               // 50 MB
  float* pre   = carve((size_t)MROWS * HID);               // 50 MB
  float* a_pub = carve((size_t)2 * NG * BPG * HID);        // 256 KB
  int*   prog  = (int*)carve((size_t)4 * NG * CPG * SLOTP); // 32 KB (4 layers)
  float* acc   = carve(64);

  (void)hipMemsetAsync(prog, 0, (size_t)4 * NG * CPG * SLOTP * sizeof(int), stream);
  init_acc<<<1, 2, 0, stream>>>(acc);

  for (int layer = 0; layer < 4; ++layer) {
    if (layer == 0) {
      gemm_mfma<3><<<dim3(HID / 128, MROWS / 128), 256, 0, stream>>>(
          x, wx0_w, wx0_b, wxbuf, MROWS, HID, 440);
    } else {
      gemm_mfma<3><<<dim3(HID / 128, MROWS / 128), 256, 0, stream>>>(
          h_all, wx_w + (size_t)(layer - 1) * HID * HID,
          wx_b + (size_t)(layer - 1) * HID, wxbuf, MROWS, HID, HID);
    }
    transpose1024<<<dim3(32, 32), dim3(32, 8), 0, stream>>>(
        uh_w + (size_t)layer * HID * HID, uhT);

    scan_layer<<<dim3(NG * CPG), 256, 0, stream>>>(
        wxbuf, uhT, h_all, pre, a_pub, prog + (size_t)layer * NG * CPG * SLOTP,
        ln_g + (size_t)layer * HID, ln_b + (size_t)layer * HID,
        (layer == 0) ? 1 : 0);
  }

  gemm_mfma<1><<<dim3((NCLS + 127) / 128, MROWS / 128), 256, 0, stream>>>(
      h_all, fco_w, fco_b, out + 2, MROWS, NCLS, HID);
  softmax_loss<<<MROWS, 256, 0, stream>>>(out + 2, lab, acc);
  finalize_out<<<1, 1, 0, stream>>>(acc, out);
}